// Round 8
// baseline (115.280 us; speedup 1.0000x reference)
//
#include <hip/hip_runtime.h>
#include <math.h>

#define NUM_CLASSES 80
#define NG 50
#define NB 8
#define RADIUS_F 1.5f
#define INF_F 1.0e8f

#define FOCAL_BLOCKS 2048
#define MAX_ASSIGN_BLOCKS 1024
// ws layout (doubles):
//   [0 .. FOCAL_BLOCKS-1]               : focal partial per focal block
//   [FOCAL_BLOCKS + flat*8 + j], j=0..4 : assign partials per assign block
//   [FOCAL_BLOCKS + MAX_ASSIGN_BLOCKS*8]: completion counter (as u32)
#define WS_ASSIGN  FOCAL_BLOCKS
#define WS_COUNTER (FOCAL_BLOCKS + MAX_ASSIGN_BLOCKS * 8)

__device__ __constant__ float c_strides[5] = {8.f, 16.f, 32.f, 64.f, 128.f};
__device__ __constant__ float c_soi[10] = {
    -1.f, 64.f,
    64.f, 128.f,
    128.f, 256.f,
    256.f, 512.f,
    512.f, INF_F
};

// focal_neg WITHOUT the 0.75 factor (applied by caller once):
//   softplus(z) * sigmoid(z)^2  -- logits ~[-9.5,1.5], e^z never overflows.
__device__ __forceinline__ float focal_neg_unscaled(float z) {
    const float u = __expf(z);                       // e^z
    const float s = 1.f + u;
    const float sp = __logf(s);                      // softplus(z)
    const float p = u * __builtin_amdgcn_rcpf(s);    // sigmoid(z)
    return sp * p * p;
}

// focal_pos(z) - focal_neg(z) for the target class (positives only)
__device__ __forceinline__ float focal_pos_minus_neg_fast(float z) {
    const float u = __expf(z);
    const float s = 1.f + u;
    const float sp = __logf(s);
    const float inv = __builtin_amdgcn_rcpf(s);      // 1 - sigmoid(z)
    const float p = u * inv;                         // sigmoid(z)
    const float fpos = (sp - z) * inv * inv * 0.25f;
    const float fneg = sp * p * p * 0.75f;
    return fpos - fneg;
}

// ---- Kernel A: label-independent focal sum over ALL logits ----
// Also zeroes the completion counter used by kernel B (B runs strictly after
// A in stream order, so this is race-free).
__global__ __launch_bounds__(256) void focal_neg_kernel(
    const float4* __restrict__ logits4,
    int total_quads,
    double* __restrict__ ws)
{
    if (blockIdx.x == 0 && threadIdx.x == 0)
        *(unsigned int*)(ws + WS_COUNTER) = 0u;

    __shared__ float red[4];
    const int stride = gridDim.x * blockDim.x;
    float acc0 = 0.f, acc1 = 0.f;
    int q = blockIdx.x * blockDim.x + threadIdx.x;
    for (; q + stride < total_quads; q += 2 * stride) {
        const float4 a = logits4[q];
        const float4 b = logits4[q + stride];
        acc0 += (focal_neg_unscaled(a.x) + focal_neg_unscaled(a.y)) +
                (focal_neg_unscaled(a.z) + focal_neg_unscaled(a.w));
        acc1 += (focal_neg_unscaled(b.x) + focal_neg_unscaled(b.y)) +
                (focal_neg_unscaled(b.z) + focal_neg_unscaled(b.w));
    }
    if (q < total_quads) {
        const float4 a = logits4[q];
        acc0 += (focal_neg_unscaled(a.x) + focal_neg_unscaled(a.y)) +
                (focal_neg_unscaled(a.z) + focal_neg_unscaled(a.w));
    }
    float acc = (acc0 + acc1) * 0.75f;   // alpha_neg factored out
    #pragma unroll
    for (int off = 32; off > 0; off >>= 1)
        acc += __shfl_down(acc, off, 64);
    const int wid = threadIdx.x >> 6;
    if ((threadIdx.x & 63) == 0) red[wid] = acc;
    __syncthreads();
    if (threadIdx.x == 0)
        ws[blockIdx.x] = (double)red[0] + red[1] + red[2] + red[3];
}

// ---- Kernel B: assignment + pos-class focal correction + GIoU + BCE,
//      with fused last-block finalize ----
__global__ __launch_bounds__(256) void fcos_assign_kernel(
    const float* __restrict__ logits,     // B*L*80
    const float* __restrict__ reg_pred,   // B*L*4
    const float* __restrict__ ctrness,    // B*L
    const float* __restrict__ locations,  // L*2
    const int*   __restrict__ level_ids,  // L
    const float* __restrict__ gt_boxes,   // B*G*4
    const int*   __restrict__ gt_classes, // B*G
    int L,
    double* __restrict__ ws,
    float* __restrict__ out)
{
    __shared__ float sb[NG * 4];
    __shared__ int   sc[NG];
    __shared__ float red[4][5];
    __shared__ int   is_last;

    const int b = blockIdx.y;
    const int l = blockIdx.x * blockDim.x + threadIdx.x;
    const int n_blocks = gridDim.x * gridDim.y;

    if (threadIdx.x < NG * 4) sb[threadIdx.x] = gt_boxes[b * NG * 4 + threadIdx.x];
    if (threadIdx.x < NG)     sc[threadIdx.x] = gt_classes[b * NG + threadIdx.x];
    __syncthreads();

    float s_cls = 0.f, s_reg = 0.f, s_ctrw = 0.f, s_bce = 0.f, s_pos = 0.f;

    if (l < L) {
        const float x = locations[l * 2 + 0];
        const float y = locations[l * 2 + 1];
        const int lvl = level_ids[l];
        const float stride = c_strides[lvl];
        const float sr = stride * RADIUS_F;
        const float lo = c_soi[lvl * 2 + 0];
        const float hi = c_soi[lvl * 2 + 1];

        float min_area = INF_F;
        int best = 0;
        #pragma unroll 5
        for (int g = 0; g < NG; ++g) {
            const float x1 = sb[g * 4 + 0], y1 = sb[g * 4 + 1];
            const float x2 = sb[g * 4 + 2], y2 = sb[g * 4 + 3];
            const float lft = x - x1, top = y - y1;
            const float rgt = x2 - x, bot = y2 - y;
            const float mx = fmaxf(fmaxf(lft, top), fmaxf(rgt, bot));
            const bool cared = (mx >= lo) && (mx <= hi);
            const float cx = (x1 + x2) * 0.5f, cy = (y1 + y2) * 0.5f;
            const float xmin = fmaxf(cx - sr, x1), ymin = fmaxf(cy - sr, y1);
            const float xmax = fminf(cx + sr, x2), ymax = fminf(cy + sr, y2);
            const float cbm = fminf(fminf(x - xmin, y - ymin), fminf(xmax - x, ymax - y));
            const bool inside = cbm > 0.f;
            const float area = (x2 - x1) * (y2 - y1);
            const float la = (inside && cared) ? area : INF_F;
            if (la < min_area) { min_area = la; best = g; }
        }
        const int label = (min_area < INF_F) ? sc[best] : NUM_CLASSES;
        const bool pos = (label < NUM_CLASSES);

        float tl = 1.f, tt = 1.f, tr = 1.f, tb = 1.f;
        if (pos) {
            const float x1 = sb[best * 4 + 0], y1 = sb[best * 4 + 1];
            const float x2 = sb[best * 4 + 2], y2 = sb[best * 4 + 3];
            const float inv = 1.0f / stride;   // stride is pow2 -> exact
            tl = (x - x1) * inv; tt = (y - y1) * inv;
            tr = (x2 - x) * inv; tb = (y2 - y) * inv;
            const float zt = logits[((size_t)b * L + l) * NUM_CLASSES + label];
            s_cls = focal_pos_minus_neg_fast(zt);
        }

        const float ctr_t = sqrtf((fminf(tl, tr) / fmaxf(tl, tr)) *
                                  (fminf(tt, tb) / fmaxf(tt, tb)));
        const float ctr_w = pos ? ctr_t : 0.f;

        const float* rp = reg_pred + ((size_t)b * L + l) * 4;
        const float pl = rp[0], pt_ = rp[1], pr = rp[2], pb = rp[3];
        const float t_area = (tl + tr) * (tt + tb);
        const float p_area = (pl + pr) * (pt_ + pb);
        const float w_i = fminf(pl, tl) + fminf(pr, tr);
        const float h_i = fminf(pt_, tt) + fminf(pb, tb);
        const float g_w = fmaxf(pl, tl) + fmaxf(pr, tr);
        const float g_h = fmaxf(pt_, tt) + fmaxf(pb, tb);
        const float a_i = w_i * h_i;
        const float a_c = g_w * g_h;
        const float a_u = t_area + p_area - a_i;
        const float ious = (a_i + 1.f) / (a_u + 1.f);
        const float gious = ious - (a_c - a_u) / fmaxf(a_c, 1e-7f);
        s_reg = (1.f - gious) * ctr_w;
        s_ctrw = ctr_w;

        const float cz = ctrness[(size_t)b * L + l];
        const float bce = __logf(1.f + __expf(cz)) - cz * ctr_w;
        s_bce = pos ? bce : 0.f;
        s_pos = pos ? 1.f : 0.f;
    }

    #pragma unroll
    for (int off = 32; off > 0; off >>= 1) {
        s_cls  += __shfl_down(s_cls,  off, 64);
        s_reg  += __shfl_down(s_reg,  off, 64);
        s_ctrw += __shfl_down(s_ctrw, off, 64);
        s_bce  += __shfl_down(s_bce,  off, 64);
        s_pos  += __shfl_down(s_pos,  off, 64);
    }
    const int wid = threadIdx.x >> 6;
    if ((threadIdx.x & 63) == 0) {
        red[wid][0] = s_cls; red[wid][1] = s_reg; red[wid][2] = s_ctrw;
        red[wid][3] = s_bce; red[wid][4] = s_pos;
    }
    __syncthreads();
    if (threadIdx.x == 0) {
        const int flat = blockIdx.y * gridDim.x + blockIdx.x;
        double* slot = ws + WS_ASSIGN + (size_t)flat * 8;
        slot[0] = (double)red[0][0] + red[1][0] + red[2][0] + red[3][0];
        slot[1] = (double)red[0][1] + red[1][1] + red[2][1] + red[3][1];
        slot[2] = (double)red[0][2] + red[1][2] + red[2][2] + red[3][2];
        slot[3] = (double)red[0][3] + red[1][3] + red[2][3] + red[3][3];
        slot[4] = (double)red[0][4] + red[1][4] + red[2][4] + red[3][4];
        __threadfence();   // publish slots before counter bump (release)
        const unsigned int v =
            atomicAdd((unsigned int*)(ws + WS_COUNTER), 1u);
        is_last = (v == (unsigned int)(n_blocks - 1)) ? 1 : 0;
    }
    __syncthreads();

    if (is_last) {
        __threadfence();   // acquire: make all blocks' slots visible
        __shared__ double dred[4][5];
        double cls = 0.0, reg = 0.0, ctrw = 0.0, bce = 0.0, np = 0.0;
        for (int i = threadIdx.x; i < FOCAL_BLOCKS; i += 256)
            cls += ws[i];
        for (int i = threadIdx.x; i < n_blocks; i += 256) {
            const double* slot = ws + WS_ASSIGN + (size_t)i * 8;
            cls  += slot[0];
            reg  += slot[1];
            ctrw += slot[2];
            bce  += slot[3];
            np   += slot[4];
        }
        #pragma unroll
        for (int off = 32; off > 0; off >>= 1) {
            cls  += __shfl_down(cls,  off, 64);
            reg  += __shfl_down(reg,  off, 64);
            ctrw += __shfl_down(ctrw, off, 64);
            bce  += __shfl_down(bce,  off, 64);
            np   += __shfl_down(np,   off, 64);
        }
        if ((threadIdx.x & 63) == 0) {
            dred[wid][0] = cls; dred[wid][1] = reg; dred[wid][2] = ctrw;
            dred[wid][3] = bce; dred[wid][4] = np;
        }
        __syncthreads();
        if (threadIdx.x == 0) {
            cls  = dred[0][0] + dred[1][0] + dred[2][0] + dred[3][0];
            reg  = dred[0][1] + dred[1][1] + dred[2][1] + dred[3][1];
            ctrw = dred[0][2] + dred[1][2] + dred[2][2] + dred[3][2];
            bce  = dred[0][3] + dred[1][3] + dred[2][3] + dred[3][3];
            np   = dred[0][4] + dred[1][4] + dred[2][4] + dred[3][4];
            const double npos = fmax(np, 1.0);
            out[0] = (float)(cls / npos);
            out[1] = (float)(reg / fmax(ctrw, 1e-6));
            out[2] = (float)(bce / npos);
        }
    }
}

extern "C" void kernel_launch(void* const* d_in, const int* in_sizes, int n_in,
                              void* d_out, int out_size, void* d_ws, size_t ws_size,
                              hipStream_t stream) {
    const float* logits     = (const float*)d_in[0];
    const float* reg_pred   = (const float*)d_in[1];
    const float* ctrness    = (const float*)d_in[2];
    const float* locations  = (const float*)d_in[3];
    const int*   level_ids  = (const int*)d_in[4];
    const float* gt_boxes   = (const float*)d_in[5];
    const int*   gt_classes = (const int*)d_in[6];
    const int L = in_sizes[4];   // level_ids: L elements

    double* ws = (double*)d_ws;
    float* out = (float*)d_out;

    const int total_quads = NB * L * (NUM_CLASSES / 4);
    focal_neg_kernel<<<FOCAL_BLOCKS, 256, 0, stream>>>(
        (const float4*)logits, total_quads, ws);

    const int gx = (L + 255) / 256;   // 67 for L=17064 -> 536 blocks total
    dim3 grid(gx, NB);
    fcos_assign_kernel<<<grid, 256, 0, stream>>>(
        logits, reg_pred, ctrness, locations, level_ids,
        gt_boxes, gt_classes, L, ws, out);
}

// Round 9
// 108.195 us; speedup vs baseline: 1.0655x; 1.0655x over previous
//
#include <hip/hip_runtime.h>
#include <math.h>

#define NUM_CLASSES 80
#define NG 50
#define NB 8
#define RADIUS_F 1.5f
#define INF_F 1.0e8f

#define FOCAL_BLOCKS 2048
// ws layout (doubles):
//   [0 .. FOCAL_BLOCKS-1]               : focal partial per focal block
//   [FOCAL_BLOCKS + flat*8 + j], j=0..4 : assign partials per assign block
#define WS_ASSIGN FOCAL_BLOCKS

__device__ __constant__ float c_strides[5] = {8.f, 16.f, 32.f, 64.f, 128.f};
__device__ __constant__ float c_soi[10] = {
    -1.f, 64.f,
    64.f, 128.f,
    128.f, 256.f,
    256.f, 512.f,
    512.f, INF_F
};

// focal_neg WITHOUT the 0.75 factor (applied by caller once):
//   softplus(z) * sigmoid(z)^2  -- logits ~[-9.5,1.5], e^z never overflows.
__device__ __forceinline__ float focal_neg_unscaled(float z) {
    const float u = __expf(z);                       // e^z
    const float s = 1.f + u;
    const float sp = __logf(s);                      // softplus(z)
    const float p = u * __builtin_amdgcn_rcpf(s);    // sigmoid(z)
    return sp * p * p;
}

// focal_pos(z) - focal_neg(z) for the target class (positives only)
__device__ __forceinline__ float focal_pos_minus_neg_fast(float z) {
    const float u = __expf(z);
    const float s = 1.f + u;
    const float sp = __logf(s);
    const float inv = __builtin_amdgcn_rcpf(s);      // 1 - sigmoid(z)
    const float p = u * inv;                         // sigmoid(z)
    const float fpos = (sp - z) * inv * inv * 0.25f;
    const float fneg = sp * p * p * 0.75f;
    return fpos - fneg;
}

// ---- Fused kernel: blocks [0,FOCAL_BLOCKS) do the label-independent focal
//      sum; blocks [FOCAL_BLOCKS, FOCAL_BLOCKS+gx*NB) do assignment+GIoU+BCE.
__global__ __launch_bounds__(256) void fcos_fused_kernel(
    const float* __restrict__ logits,     // B*L*80
    const float* __restrict__ reg_pred,   // B*L*4
    const float* __restrict__ ctrness,    // B*L
    const float* __restrict__ locations,  // L*2
    const int*   __restrict__ level_ids,  // L
    const float* __restrict__ gt_boxes,   // B*G*4
    const int*   __restrict__ gt_classes, // B*G
    int L, int gx,
    double* __restrict__ ws)
{
    if (blockIdx.x < FOCAL_BLOCKS) {
        // ================= focal path =================
        __shared__ float red[4];
        const float4* logits4 = (const float4*)logits;
        const int total_quads = NB * L * (NUM_CLASSES / 4);
        const int stride = FOCAL_BLOCKS * 256;
        float acc0 = 0.f, acc1 = 0.f;
        int q = blockIdx.x * 256 + threadIdx.x;
        for (; q + stride < total_quads; q += 2 * stride) {
            const float4 a = logits4[q];
            const float4 b = logits4[q + stride];
            acc0 += (focal_neg_unscaled(a.x) + focal_neg_unscaled(a.y)) +
                    (focal_neg_unscaled(a.z) + focal_neg_unscaled(a.w));
            acc1 += (focal_neg_unscaled(b.x) + focal_neg_unscaled(b.y)) +
                    (focal_neg_unscaled(b.z) + focal_neg_unscaled(b.w));
        }
        if (q < total_quads) {
            const float4 a = logits4[q];
            acc0 += (focal_neg_unscaled(a.x) + focal_neg_unscaled(a.y)) +
                    (focal_neg_unscaled(a.z) + focal_neg_unscaled(a.w));
        }
        float acc = (acc0 + acc1) * 0.75f;   // alpha_neg factored out
        #pragma unroll
        for (int off = 32; off > 0; off >>= 1)
            acc += __shfl_down(acc, off, 64);
        const int wid = threadIdx.x >> 6;
        if ((threadIdx.x & 63) == 0) red[wid] = acc;
        __syncthreads();
        if (threadIdx.x == 0)
            ws[blockIdx.x] = (double)red[0] + red[1] + red[2] + red[3];
        return;
    }

    // ================= assign path =================
    __shared__ float sb[NG * 4];
    __shared__ int   sc[NG];
    __shared__ float red[4][5];

    const int flat = blockIdx.x - FOCAL_BLOCKS;   // 0 .. gx*NB-1
    const int b = flat / gx;
    const int l = (flat - b * gx) * 256 + threadIdx.x;

    if (threadIdx.x < NG * 4) sb[threadIdx.x] = gt_boxes[b * NG * 4 + threadIdx.x];
    if (threadIdx.x < NG)     sc[threadIdx.x] = gt_classes[b * NG + threadIdx.x];
    __syncthreads();

    float s_cls = 0.f, s_reg = 0.f, s_ctrw = 0.f, s_bce = 0.f, s_pos = 0.f;

    if (l < L) {
        const float x = locations[l * 2 + 0];
        const float y = locations[l * 2 + 1];
        const int lvl = level_ids[l];
        const float stride = c_strides[lvl];
        const float sr = stride * RADIUS_F;
        const float lo = c_soi[lvl * 2 + 0];
        const float hi = c_soi[lvl * 2 + 1];

        float min_area = INF_F;
        int best = 0;
        #pragma unroll 5
        for (int g = 0; g < NG; ++g) {
            const float x1 = sb[g * 4 + 0], y1 = sb[g * 4 + 1];
            const float x2 = sb[g * 4 + 2], y2 = sb[g * 4 + 3];
            const float lft = x - x1, top = y - y1;
            const float rgt = x2 - x, bot = y2 - y;
            const float mx = fmaxf(fmaxf(lft, top), fmaxf(rgt, bot));
            const bool cared = (mx >= lo) && (mx <= hi);
            const float cx = (x1 + x2) * 0.5f, cy = (y1 + y2) * 0.5f;
            const float xmin = fmaxf(cx - sr, x1), ymin = fmaxf(cy - sr, y1);
            const float xmax = fminf(cx + sr, x2), ymax = fminf(cy + sr, y2);
            const float cbm = fminf(fminf(x - xmin, y - ymin), fminf(xmax - x, ymax - y));
            const bool inside = cbm > 0.f;
            const float area = (x2 - x1) * (y2 - y1);
            const float la = (inside && cared) ? area : INF_F;
            if (la < min_area) { min_area = la; best = g; }
        }
        const int label = (min_area < INF_F) ? sc[best] : NUM_CLASSES;
        const bool pos = (label < NUM_CLASSES);

        float tl = 1.f, tt = 1.f, tr = 1.f, tb = 1.f;
        if (pos) {
            const float x1 = sb[best * 4 + 0], y1 = sb[best * 4 + 1];
            const float x2 = sb[best * 4 + 2], y2 = sb[best * 4 + 3];
            const float inv = 1.0f / stride;   // stride is pow2 -> exact
            tl = (x - x1) * inv; tt = (y - y1) * inv;
            tr = (x2 - x) * inv; tb = (y2 - y) * inv;
            const float zt = logits[((size_t)b * L + l) * NUM_CLASSES + label];
            s_cls = focal_pos_minus_neg_fast(zt);
        }

        const float ctr_t = sqrtf((fminf(tl, tr) / fmaxf(tl, tr)) *
                                  (fminf(tt, tb) / fmaxf(tt, tb)));
        const float ctr_w = pos ? ctr_t : 0.f;

        const float* rp = reg_pred + ((size_t)b * L + l) * 4;
        const float pl = rp[0], pt_ = rp[1], pr = rp[2], pb = rp[3];
        const float t_area = (tl + tr) * (tt + tb);
        const float p_area = (pl + pr) * (pt_ + pb);
        const float w_i = fminf(pl, tl) + fminf(pr, tr);
        const float h_i = fminf(pt_, tt) + fminf(pb, tb);
        const float g_w = fmaxf(pl, tl) + fmaxf(pr, tr);
        const float g_h = fmaxf(pt_, tt) + fmaxf(pb, tb);
        const float a_i = w_i * h_i;
        const float a_c = g_w * g_h;
        const float a_u = t_area + p_area - a_i;
        const float ious = (a_i + 1.f) / (a_u + 1.f);
        const float gious = ious - (a_c - a_u) / fmaxf(a_c, 1e-7f);
        s_reg = (1.f - gious) * ctr_w;
        s_ctrw = ctr_w;

        const float cz = ctrness[(size_t)b * L + l];
        const float bce = __logf(1.f + __expf(cz)) - cz * ctr_w;
        s_bce = pos ? bce : 0.f;
        s_pos = pos ? 1.f : 0.f;
    }

    #pragma unroll
    for (int off = 32; off > 0; off >>= 1) {
        s_cls  += __shfl_down(s_cls,  off, 64);
        s_reg  += __shfl_down(s_reg,  off, 64);
        s_ctrw += __shfl_down(s_ctrw, off, 64);
        s_bce  += __shfl_down(s_bce,  off, 64);
        s_pos  += __shfl_down(s_pos,  off, 64);
    }
    const int wid = threadIdx.x >> 6;
    if ((threadIdx.x & 63) == 0) {
        red[wid][0] = s_cls; red[wid][1] = s_reg; red[wid][2] = s_ctrw;
        red[wid][3] = s_bce; red[wid][4] = s_pos;
    }
    __syncthreads();
    if (threadIdx.x == 0) {
        double* slot = ws + WS_ASSIGN + (size_t)flat * 8;
        slot[0] = (double)red[0][0] + red[1][0] + red[2][0] + red[3][0];
        slot[1] = (double)red[0][1] + red[1][1] + red[2][1] + red[3][1];
        slot[2] = (double)red[0][2] + red[1][2] + red[2][2] + red[3][2];
        slot[3] = (double)red[0][3] + red[1][3] + red[2][3] + red[3][3];
        slot[4] = (double)red[0][4] + red[1][4] + red[2][4] + red[3][4];
    }
}

// ---- finalize: sum per-block slots, compute the 3 losses ----
__global__ __launch_bounds__(256) void finalize_kernel(
    const double* __restrict__ ws,
    int n_assign_blocks,
    float* __restrict__ out)
{
    __shared__ double red[4][6];
    double cls = 0.0, reg = 0.0, ctrw = 0.0, bce = 0.0, np = 0.0;
    for (int i = threadIdx.x; i < FOCAL_BLOCKS; i += 256)
        cls += ws[i];
    for (int i = threadIdx.x; i < n_assign_blocks; i += 256) {
        const double* slot = ws + WS_ASSIGN + (size_t)i * 8;
        cls  += slot[0];
        reg  += slot[1];
        ctrw += slot[2];
        bce  += slot[3];
        np   += slot[4];
    }
    #pragma unroll
    for (int off = 32; off > 0; off >>= 1) {
        cls  += __shfl_down(cls,  off, 64);
        reg  += __shfl_down(reg,  off, 64);
        ctrw += __shfl_down(ctrw, off, 64);
        bce  += __shfl_down(bce,  off, 64);
        np   += __shfl_down(np,   off, 64);
    }
    const int wid = threadIdx.x >> 6;
    if ((threadIdx.x & 63) == 0) {
        red[wid][0] = cls; red[wid][1] = reg; red[wid][2] = ctrw;
        red[wid][3] = bce; red[wid][4] = np;
    }
    __syncthreads();
    if (threadIdx.x == 0) {
        cls  = red[0][0] + red[1][0] + red[2][0] + red[3][0];
        reg  = red[0][1] + red[1][1] + red[2][1] + red[3][1];
        ctrw = red[0][2] + red[1][2] + red[2][2] + red[3][2];
        bce  = red[0][3] + red[1][3] + red[2][3] + red[3][3];
        np   = red[0][4] + red[1][4] + red[2][4] + red[3][4];
        const double npos = fmax(np, 1.0);
        out[0] = (float)(cls / npos);
        out[1] = (float)(reg / fmax(ctrw, 1e-6));
        out[2] = (float)(bce / npos);
    }
}

extern "C" void kernel_launch(void* const* d_in, const int* in_sizes, int n_in,
                              void* d_out, int out_size, void* d_ws, size_t ws_size,
                              hipStream_t stream) {
    const float* logits     = (const float*)d_in[0];
    const float* reg_pred   = (const float*)d_in[1];
    const float* ctrness    = (const float*)d_in[2];
    const float* locations  = (const float*)d_in[3];
    const int*   level_ids  = (const int*)d_in[4];
    const float* gt_boxes   = (const float*)d_in[5];
    const int*   gt_classes = (const int*)d_in[6];
    const int L = in_sizes[4];   // level_ids: L elements

    double* ws = (double*)d_ws;
    float* out = (float*)d_out;

    const int gx = (L + 255) / 256;   // 67 for L=17064
    const int n_assign = gx * NB;     // 536

    fcos_fused_kernel<<<FOCAL_BLOCKS + n_assign, 256, 0, stream>>>(
        logits, reg_pred, ctrness, locations, level_ids,
        gt_boxes, gt_classes, L, gx, ws);

    finalize_kernel<<<1, 256, 0, stream>>>(ws, n_assign, out);
}